// Round 8
// baseline (3187.464 us; speedup 1.0000x reference)
//
#include <hip/hip_runtime.h>
#include <stdint.h>

#define B_ 64
#define T_ 512
#define I_ 128
#define H_ 512
#define O_ 64
#define ALPHA_ 0.1f

// K-split recurrence: 8 waves; wave wv owns h-pair slice [32wv, 32wv+32)
// (= 8 h-quads q0..q7). Lane l partial-dots rows {64j+l}, j=0..7.
// Per lane 256 weight pairs: quads q0..q3 resident (wr[8][16] = 128 VGPRs),
// quads q4..q7 streamed from L2 every step (8 chunks x 4 dwordx4, fenced,
// <=3 chunks live; chunk q4 is loop-carried across the barrier).
#define CV 16
#define R_DW (128 * 512)            // wrecR dwords
#define S_END (R_DW + 128 * 512)    // + wrecS dwords
#define WIN_END (S_END + 512 * 64)

typedef _Float16 f16;
typedef _Float16 f16x2 __attribute__((ext_vector_type(2)));

__device__ __forceinline__ uint32_t pkf16(float a, float b) {
  f16 ha = (f16)a, hb = (f16)b;
  uint16_t ua = __builtin_bit_cast(uint16_t, ha);
  uint16_t ub = __builtin_bit_cast(uint16_t, hb);
  return (uint32_t)ua | ((uint32_t)ub << 16);
}

__device__ __forceinline__ float dot2(uint32_t w, uint32_t h, float acc) {
#if __has_builtin(__builtin_amdgcn_fdot2)
  return __builtin_amdgcn_fdot2(__builtin_bit_cast(f16x2, w),
                                __builtin_bit_cast(f16x2, h), acc, false);
#else
  f16x2 wv = __builtin_bit_cast(f16x2, w), hv = __builtin_bit_cast(f16x2, h);
  return acc + (float)wv[0] * (float)hv[0] + (float)wv[1] * (float)hv[1];
#endif
}

__device__ __forceinline__ float tanhfast(float x) {
  float e = __expf(2.0f * x);   // inf-safe at both ends
#if __has_builtin(__builtin_amdgcn_rcpf)
  return 1.0f - 2.0f * __builtin_amdgcn_rcpf(e + 1.0f);
#else
  return 1.0f - 2.0f / (e + 1.0f);
#endif
}

// Consume one streamed uint4 (4 pairs) against h-quad hq into acc slot.
#define DOT4S(A, S, HQ)                                             \
  A = dot2((S).w, (HQ).w,                                           \
      dot2((S).z, (HQ).z, dot2((S).y, (HQ).y, dot2((S).x, (HQ).x, A))))

// ---------------------------------------------------------------------------
// Pack weights (f16x2 pairs):
//  wrecR[(j*16+c)*512 + t]  = W_rec[64j+(t&63)][ 2*(32*(t>>6)+c) ..+1], c<16
//  wrecS (uint4): idx4 = (cc*4+jj)*512 + t, comp q:
//     cc=0..7: qd=4+(cc>>1), h=cc&1, j=4h+jj
//     = W_rec[64j+(t&63)][ 2*(32*(t>>6)+4*qd+comp) ..+1]
//  winT [k*512 + n] = W_in[n][2k..+1]
//  woutT[k*64  + o] = W_out[o][2k..+1]
// ---------------------------------------------------------------------------
__global__ __launch_bounds__(256) void pack_w(
    const float* __restrict__ Wrec, const float* __restrict__ Win,
    const float* __restrict__ Wout, uint32_t* __restrict__ wrecR,
    uint32_t* __restrict__ wrecS, uint32_t* __restrict__ winT,
    uint32_t* __restrict__ woutT) {
  int id = blockIdx.x * 256 + threadIdx.x;
  if (id < R_DW) {
    int t = id & 511, cj = id >> 9;
    int j = cj >> 4, c = cj & 15;
    int row = 64 * j + (t & 63), col = 64 * (t >> 6) + 2 * c;
    const float* s = Wrec + row * 512 + col;
    wrecR[id] = pkf16(s[0], s[1]);
  } else if (id < S_END) {
    int e = id - R_DW;
    int comp = e & 3, i4 = e >> 2;
    int t = i4 & 511, cj = i4 >> 9;           // cj in [0,32)
    int cc = cj >> 2, jj = cj & 3;
    int qd = 4 + (cc >> 1), h = cc & 1, j = 4 * h + jj;
    int row = 64 * j + (t & 63);
    int col = 64 * (t >> 6) + 2 * (4 * qd + comp);
    const float* s = Wrec + row * 512 + col;
    wrecS[e] = pkf16(s[0], s[1]);
  } else if (id < WIN_END) {
    int e = id - S_END;
    int n = e >> 6, k = e & 63;
    const float* s = Win + n * 128 + 2 * k;
    winT[k * 512 + n] = pkf16(s[0], s[1]);
  } else {
    int e = id - WIN_END;
    int o = e >> 8, k = e & 255;
    const float* s = Wout + o * 512 + 2 * k;
    woutT[k * 64 + o] = pkf16(s[0], s[1]);
  }
}

// ---------------------------------------------------------------------------
// x_proj: xp[m, n] = sum_i inputs[m, i] * W_in[n, i]   (m = b*T+ts, f16 out)
// ---------------------------------------------------------------------------
__global__ __launch_bounds__(512) void xproj_k(
    const float* __restrict__ in, const uint32_t* __restrict__ winT,
    f16* __restrict__ xp) {
  __shared__ uint32_t A[32][64];
  const int t = threadIdx.x;
  const int m0 = blockIdx.x * 32;
#pragma unroll
  for (int i = 0; i < 4; i++) {
    int id = i * 512 + t;
    int r = id >> 6, k = id & 63;
    const float* s = in + (m0 + r) * I_ + 2 * k;
    A[r][k] = pkf16(s[0], s[1]);
  }
  uint32_t w[64];
#pragma unroll
  for (int k = 0; k < 64; k++) w[k] = winT[k * 512 + t];
  __syncthreads();
  for (int r = 0; r < 32; r++) {
    float a0 = 0.f, a1 = 0.f, a2 = 0.f, a3 = 0.f;
#pragma unroll
    for (int k4 = 0; k4 < 16; k4++) {
      uint4 hq = *((const uint4*)&A[r][k4 * 4]);
      a0 = dot2(w[4 * k4 + 0], hq.x, a0);
      a1 = dot2(w[4 * k4 + 1], hq.y, a1);
      a2 = dot2(w[4 * k4 + 2], hq.z, a2);
      a3 = dot2(w[4 * k4 + 3], hq.w, a3);
    }
    xp[(m0 + r) * H_ + t] = (f16)((a0 + a1) + (a2 + a3));
  }
}

// ---------------------------------------------------------------------------
// Recurrence, K-split + fenced L2 weight streaming, ONE barrier per step.
//  - hbuf single-buffered: wave wv reads ONLY h[64wv..64wv+64), which its own
//    lanes wrote (intra-wave lgkm ordering, no barrier needed).
//  - pld double-buffered => one lgkm-only barrier/step (vm stays in flight).
//  - stream chunks: 8 x (4 x dwordx4); sched_barrier(0) after each block
//    bounds live ranges (anti-hoist, the r7 spill cause); chunk q4 (p0,p1)
//    is issued at the END of the step and consumed early next step.
// ---------------------------------------------------------------------------
__global__ __attribute__((amdgpu_flat_work_group_size(512, 512),
                          amdgpu_waves_per_eu(2, 2)))
void rnn_k(const uint32_t* __restrict__ wrecR, const uint4* __restrict__ wrecS,
           const f16* __restrict__ xp, const float* __restrict__ bias,
           const float* __restrict__ h0, f16* __restrict__ hall,
           float* __restrict__ hfin) {
  __shared__ uint32_t hbuf[256];      // 256 f16x2 pairs = h[512]
  __shared__ float pld[2][8][512];    // partials [buf][slice][row], 32 KB
  const int b = blockIdx.x, t = threadIdx.x;
  const int l = t & 63, wv = t >> 6;

  uint32_t wr[8][CV];  // quads q0..q3 resident: 128 VGPRs
#pragma unroll
  for (int j = 0; j < 8; j++)
#pragma unroll
    for (int c = 0; c < CV; c++) wr[j][c] = wrecR[((j << 4) + c) * 512 + t];

  float hv = h0[b * H_ + t];
  const float bia = bias[t];
  ((f16*)hbuf)[t] = (f16)hv;

  const f16* xpp = xp + b * (T_ * H_) + t;
  f16* hap = hall + b * H_ + t;
  float xv = (float)xpp[0];
  const uint4* sQ = wrecS + t;
  const uint32_t* hqb = hbuf + (wv << 5);
  float* pwb = &pld[0][wv][l];
  const float* prb = &pld[0][0][t];

  // prologue: chunk q4 (rows 0-3 -> p0, rows 4-7 -> p1) in flight
  uint4 p0[4], p1[4];
#pragma unroll
  for (int jj = 0; jj < 4; jj++) {
    p0[jj] = sQ[(0 * 4 + jj) << 9];
    p1[jj] = sQ[(1 * 4 + jj) << 9];
  }
  __syncthreads();

  int p = 0;
  for (int ts = 0; ts < T_; ++ts) {
    float acc[8];
#pragma unroll
    for (int j = 0; j < 8; j++) acc[j] = 0.f;
    // ---- B1: resident q0,q1; issue chunks s2,s3 (quad5) ----
    {
      uint4 hq = *((const uint4*)(hqb + 0));
#pragma unroll
      for (int j = 0; j < 8; j++)
        acc[j] = dot2(wr[j][3], hq.w, dot2(wr[j][2], hq.z,
                 dot2(wr[j][1], hq.y, dot2(wr[j][0], hq.x, acc[j]))));
    }
    {
      uint4 hq = *((const uint4*)(hqb + 4));
#pragma unroll
      for (int j = 0; j < 8; j++)
        acc[j] = dot2(wr[j][7], hq.w, dot2(wr[j][6], hq.z,
                 dot2(wr[j][5], hq.y, dot2(wr[j][4], hq.x, acc[j]))));
    }
    uint4 s2[4], s3[4];
#pragma unroll
    for (int jj = 0; jj < 4; jj++) {
      s2[jj] = sQ[(2 * 4 + jj) << 9];
      s3[jj] = sQ[(3 * 4 + jj) << 9];
    }
    __builtin_amdgcn_sched_barrier(0);
    // ---- B2: consume p0,p1 (quad4); resident q2; issue s4,s5 (quad6) ----
    {
      uint4 hq = *((const uint4*)(hqb + 16));
#pragma unroll
      for (int jj = 0; jj < 4; jj++) {
        DOT4S(acc[jj], p0[jj], hq);
        DOT4S(acc[4 + jj], p1[jj], hq);
      }
    }
    uint4 s4[4], s5[4];
#pragma unroll
    for (int jj = 0; jj < 4; jj++) {
      s4[jj] = sQ[(4 * 4 + jj) << 9];
      s5[jj] = sQ[(5 * 4 + jj) << 9];
    }
    {
      uint4 hq = *((const uint4*)(hqb + 8));
#pragma unroll
      for (int j = 0; j < 8; j++)
        acc[j] = dot2(wr[j][11], hq.w, dot2(wr[j][10], hq.z,
                 dot2(wr[j][9], hq.y, dot2(wr[j][8], hq.x, acc[j]))));
    }
    __builtin_amdgcn_sched_barrier(0);
    // ---- B3: consume s2,s3 (quad5); resident q3; issue s6,s7 (quad7) ----
    {
      uint4 hq = *((const uint4*)(hqb + 20));
#pragma unroll
      for (int jj = 0; jj < 4; jj++) {
        DOT4S(acc[jj], s2[jj], hq);
        DOT4S(acc[4 + jj], s3[jj], hq);
      }
    }
    uint4 s6[4], s7[4];
#pragma unroll
    for (int jj = 0; jj < 4; jj++) {
      s6[jj] = sQ[(6 * 4 + jj) << 9];
      s7[jj] = sQ[(7 * 4 + jj) << 9];
    }
    {
      uint4 hq = *((const uint4*)(hqb + 12));
#pragma unroll
      for (int j = 0; j < 8; j++)
        acc[j] = dot2(wr[j][15], hq.w, dot2(wr[j][14], hq.z,
                 dot2(wr[j][13], hq.y, dot2(wr[j][12], hq.x, acc[j]))));
    }
    __builtin_amdgcn_sched_barrier(0);
    // ---- B4: consume s4,s5 (quad6); issue NEXT-step p0,p1 (quad4) ----
    {
      uint4 hq = *((const uint4*)(hqb + 24));
#pragma unroll
      for (int jj = 0; jj < 4; jj++) {
        DOT4S(acc[jj], s4[jj], hq);
        DOT4S(acc[4 + jj], s5[jj], hq);
      }
    }
#pragma unroll
    for (int jj = 0; jj < 4; jj++) {
      p0[jj] = sQ[(0 * 4 + jj) << 9];
      p1[jj] = sQ[(1 * 4 + jj) << 9];
    }
    __builtin_amdgcn_sched_barrier(0);
    // ---- B5: consume s6,s7 (quad7); partial writes; barrier ----
    {
      uint4 hq = *((const uint4*)(hqb + 28));
#pragma unroll
      for (int jj = 0; jj < 4; jj++) {
        DOT4S(acc[jj], s6[jj], hq);
        DOT4S(acc[4 + jj], s7[jj], hq);
      }
    }
    float* pw = pwb + (p << 12);
#pragma unroll
    for (int j = 0; j < 8; j++) pw[j << 6] = acc[j];  // conflict-free b32
    float xn = 0.f;
    if (ts + 1 < T_) xn = (float)xpp[(ts + 1) * H_];  // vm, rides barrier
    asm volatile("s_waitcnt lgkmcnt(0)" ::: "memory");
    __builtin_amdgcn_s_barrier();
    asm volatile("" ::: "memory");
    // ---- reduce row t; h update; intra-wave h publish ----
    const float* pr = prb + (p << 12);
    float s01 = pr[0 << 9] + pr[1 << 9], s23 = pr[2 << 9] + pr[3 << 9];
    float s45 = pr[4 << 9] + pr[5 << 9], s67 = pr[6 << 9] + pr[7 << 9];
    float pre = ((s01 + s23) + (s45 + s67)) + bia + xv;
    hv = (1.0f - ALPHA_) * hv + ALPHA_ * tanhfast(pre);
    f16 hh = (f16)hv;
    ((f16*)hbuf)[t] = hh;        // own-wave consumers only
    hap[ts * (B_ * H_)] = hh;    // hall[ts][b][t] (vm)
    xv = xn;
    p ^= 1;
    asm volatile("s_waitcnt lgkmcnt(0)" ::: "memory");  // h write retired
    __builtin_amdgcn_sched_barrier(0);
  }
  hfin[b * H_ + t] = hv;
}

// ---------------------------------------------------------------------------
// out[b, ts, o] = sum_h hall[ts][b][h] * W_out[o, h] + b_out[o]
// ---------------------------------------------------------------------------
__global__ __launch_bounds__(256) void outgemm_k(
    const f16* __restrict__ hall, const uint32_t* __restrict__ woutT,
    const float* __restrict__ bout, float* __restrict__ out) {
  __shared__ uint32_t A[32][256];
  const int bid = blockIdx.x;
  const int b = bid >> 4, ts0 = (bid & 15) * 32;
  const int t = threadIdx.x, o = t & 63, g = t >> 6;
  const uint32_t* hp = (const uint32_t*)hall;
#pragma unroll
  for (int i = 0; i < 32; i++) {
    int id = i * 256 + t;
    int r = id >> 8, k = id & 255;
    A[r][k] = hp[(ts0 + r) * (B_ * H_ / 2) + b * (H_ / 2) + k];
  }
  const float bo = bout[o];
  __syncthreads();
  float acc[8];
#pragma unroll
  for (int r = 0; r < 8; r++) acc[r] = 0.f;
  for (int k4 = 0; k4 < 64; k4++) {
    uint32_t w0 = woutT[(4 * k4 + 0) * 64 + o];
    uint32_t w1 = woutT[(4 * k4 + 1) * 64 + o];
    uint32_t w2 = woutT[(4 * k4 + 2) * 64 + o];
    uint32_t w3 = woutT[(4 * k4 + 3) * 64 + o];
#pragma unroll
    for (int r = 0; r < 8; r++) {
      uint4 hq = *((const uint4*)&A[g * 8 + r][k4 * 4]);
      acc[r] = dot2(w0, hq.x, acc[r]);
      acc[r] = dot2(w1, hq.y, acc[r]);
      acc[r] = dot2(w2, hq.z, acc[r]);
      acc[r] = dot2(w3, hq.w, acc[r]);
    }
  }
#pragma unroll
  for (int r = 0; r < 8; r++)
    out[(b * T_ + ts0 + g * 8 + r) * O_ + o] = acc[r] + bo;
}

extern "C" void kernel_launch(void* const* d_in, const int* in_sizes, int n_in,
                              void* d_out, int out_size, void* d_ws,
                              size_t ws_size, hipStream_t stream) {
  const float* inputs = (const float*)d_in[0];  // [B,T,I]
  const float* h0     = (const float*)d_in[1];  // [B,H]
  const float* Win    = (const float*)d_in[2];  // [H,I]
  const float* Wrec   = (const float*)d_in[3];  // [H,H]
  const float* bias   = (const float*)d_in[4];  // [H]
  const float* Wout   = (const float*)d_in[5];  // [O,H]
  const float* bout   = (const float*)d_in[6];  // [O]
  float* out = (float*)d_out;                   // [B,T,O] then [B,H]

  uint8_t* ws = (uint8_t*)d_ws;
  uint32_t* wrecR = (uint32_t*)(ws);                      // 256 KB
  uint32_t* wrecS = (uint32_t*)(ws + (256u << 10));       // 256 KB
  uint32_t* winT  = (uint32_t*)(ws + (512u << 10));       // 128 KB
  uint32_t* woutT = (uint32_t*)(ws + (640u << 10));       //  64 KB
  f16* xp   = (f16*)(ws + (1u << 20));                    //  32 MB [B,T,H]
  f16* hall = (f16*)(ws + (1u << 20) + (32u << 20));      //  32 MB [T,B,H]

  hipLaunchKernelGGL(pack_w, dim3(704), dim3(256), 0, stream, Wrec, Win, Wout,
                     wrecR, wrecS, winT, woutT);
  hipLaunchKernelGGL(xproj_k, dim3(32768 / 32), dim3(512), 0, stream, inputs,
                     winT, xp);
  hipLaunchKernelGGL(rnn_k, dim3(B_), dim3(512), 0, stream, wrecR,
                     (const uint4*)wrecS, xp, bias, h0, hall,
                     out + B_ * T_ * O_);
  hipLaunchKernelGGL(outgemm_k, dim3(B_ * (T_ / 32)), dim3(256), 0, stream,
                     hall, woutT, bout, out);
}

// Round 9
// 2637.590 us; speedup vs baseline: 1.2085x; 1.2085x over previous
//
#include <hip/hip_runtime.h>
#include <stdint.h>

#define B_ 64
#define T_ 512
#define I_ 128
#define H_ 512
#define O_ 64
#define ALPHA_ 0.1f

typedef _Float16 f16;
typedef _Float16 f16x8 __attribute__((ext_vector_type(8)));
typedef float f32x4 __attribute__((ext_vector_type(4)));

// wrecM: MFMA B-fragments, u32 pairs. id -> p=id&3, l=(id>>2)&63,
//   kk=(id>>8)&15, r2w=id>>12 (0..31):
//   row = (r2w>>1)*32 + (r2w&1)*16 + (l&15)   [output row n]
//   col = kk*32 + (l>>4)*8 + 2p               [k index]
#define WRECM_U32 131072
#define WIN_END   (WRECM_U32 + 32768)
#define WOUT_END  (WIN_END + 16384)

__device__ __forceinline__ uint32_t pkf16(float a, float b) {
  f16 ha = (f16)a, hb = (f16)b;
  uint16_t ua = __builtin_bit_cast(uint16_t, ha);
  uint16_t ub = __builtin_bit_cast(uint16_t, hb);
  return (uint32_t)ua | ((uint32_t)ub << 16);
}

__device__ __forceinline__ float dot2(uint32_t w, uint32_t h, float acc) {
#if __has_builtin(__builtin_amdgcn_fdot2)
  typedef _Float16 f16x2 __attribute__((ext_vector_type(2)));
  return __builtin_amdgcn_fdot2(__builtin_bit_cast(f16x2, w),
                                __builtin_bit_cast(f16x2, h), acc, false);
#else
  return acc;
#endif
}

__device__ __forceinline__ float tanhfast(float x) {
  float e = __expf(2.0f * x);
#if __has_builtin(__builtin_amdgcn_rcpf)
  return 1.0f - 2.0f * __builtin_amdgcn_rcpf(e + 1.0f);
#else
  return 1.0f - 2.0f / (e + 1.0f);
#endif
}

// ---------------------------------------------------------------------------
__global__ __launch_bounds__(256) void pack_w(
    const float* __restrict__ Wrec, const float* __restrict__ Win,
    const float* __restrict__ Wout, uint32_t* __restrict__ wrecM,
    uint32_t* __restrict__ winT, uint32_t* __restrict__ woutT) {
  int id = blockIdx.x * 256 + threadIdx.x;
  if (id < WRECM_U32) {
    int p = id & 3, l = (id >> 2) & 63, kk = (id >> 8) & 15, r2w = id >> 12;
    int row = (r2w >> 1) * 32 + (r2w & 1) * 16 + (l & 15);
    int col = kk * 32 + (l >> 4) * 8 + 2 * p;
    const float* s = Wrec + row * 512 + col;
    wrecM[id] = pkf16(s[0], s[1]);
  } else if (id < WIN_END) {
    int e = id - WRECM_U32;
    int n = e >> 6, k = e & 63;
    const float* s = Win + n * 128 + 2 * k;
    winT[k * 512 + n] = pkf16(s[0], s[1]);
  } else if (id < WOUT_END) {
    int e = id - WIN_END;
    int o = e >> 8, k = e & 255;
    const float* s = Wout + o * 512 + 2 * k;
    woutT[k * 64 + o] = pkf16(s[0], s[1]);
  }
}

// ---------------------------------------------------------------------------
// x_proj with bias folded: xpb[ts][b][n] = sum_i in[b,ts,i]*W_in[n,i] + b[n]
// ---------------------------------------------------------------------------
__global__ __launch_bounds__(512) void xproj_k(
    const float* __restrict__ in, const uint32_t* __restrict__ winT,
    const float* __restrict__ bias, f16* __restrict__ xpb) {
  __shared__ uint32_t A[32][64];
  const int t = threadIdx.x;
  const int m0 = blockIdx.x * 32;
#pragma unroll
  for (int i = 0; i < 4; i++) {
    int id = i * 512 + t;
    int r = id >> 6, k = id & 63;
    const float* s = in + (m0 + r) * I_ + 2 * k;
    A[r][k] = pkf16(s[0], s[1]);
  }
  uint32_t w[64];
#pragma unroll
  for (int k = 0; k < 64; k++) w[k] = winT[k * 512 + t];
  const float bia = bias[t];
  __syncthreads();
  for (int r = 0; r < 32; r++) {
    float a0 = 0.f, a1 = 0.f, a2 = 0.f, a3 = 0.f;
#pragma unroll
    for (int k4 = 0; k4 < 16; k4++) {
      uint4 hq = *((const uint4*)&A[r][k4 * 4]);
      a0 = dot2(w[4 * k4 + 0], hq.x, a0);
      a1 = dot2(w[4 * k4 + 1], hq.y, a1);
      a2 = dot2(w[4 * k4 + 2], hq.z, a2);
      a3 = dot2(w[4 * k4 + 3], hq.w, a3);
    }
    int m = m0 + r, b = m >> 9, ts = m & 511;
    xpb[(((ts << 6) + b) << 9) + t] = (f16)(((a0 + a1) + (a2 + a3)) + bia);
  }
}

// ---------------------------------------------------------------------------
// Recurrence via MFMA: 64 WGs = 4 batch-groups (c) x 16 h-slices (r), 128 thr
// = 2 waves. Wave w computes pre[batch 16][rows r*32+w*16 .. +16] as
// D = A(h[16,512]) x B(W^T) with 16 chained mfma_f32_16x16x32_f16.
// B fragments (64 VGPR/lane) loaded ONCE. A staged per step via
// global_load_lds (per-lane src = A-fragment addr, linear LDS dest).
// Step barrier: per-group flag, device-scope release add + acquire spin.
// ---------------------------------------------------------------------------
__global__ __launch_bounds__(128) void rnn_k(
    const f16x8* __restrict__ wrecM, const f16* __restrict__ xpb,
    const float* __restrict__ h0, f16* __restrict__ h_ex,
    uint32_t* __restrict__ flags, float* __restrict__ hfin) {
  __shared__ f16 lds_a[2][16][512];  // [wave][kk][A-frag 1KB] = 32 KB
  const int bid = blockIdx.x, c = bid & 3, r = bid >> 2;
  const int t = threadIdx.x, l = t & 63, w = t >> 6;
  const int lo = l & 15, hi = l >> 4;
  const int b0 = c << 4;
  const int myrow = (r << 5) + (w << 4) + lo;  // output row n of this lane

  // resident B fragments: Bf[kk][j] = W_rec[myrow][kk*32 + hi*8 + j]
  f16x8 Bf[16];
  const f16x8* wp = wrecM + ((((r << 1) + w) << 4) << 6) + l;
#pragma unroll
  for (int kk = 0; kk < 16; kk++) Bf[kk] = wp[kk << 6];

  // master h (f32): lane owns batch b0+hi*4+reg (reg=0..3), row myrow
  float hv0, hv1, hv2, hv3;
  {
    const float* hp = h0 + (b0 + (hi << 2)) * H_ + myrow;
    hv0 = hp[0]; hv1 = hp[H_]; hv2 = hp[2 * H_]; hv3 = hp[3 * H_];
    f16* he = h_ex + (b0 + (hi << 2)) * H_ + myrow;
    he[0] = (f16)hv0; he[H_] = (f16)hv1;
    he[2 * H_] = (f16)hv2; he[3 * H_] = (f16)hv3;
  }
  uint32_t* flg = flags + (c << 5);  // 128-B spaced per group
  __syncthreads();
  if (t == 0)
    __hip_atomic_fetch_add(flg, 1u, __ATOMIC_RELEASE, __HIP_MEMORY_SCOPE_AGENT);

  // A source: lane reads h_ex[ts][b0+lo][kk*32 + hi*8 .. +8]
  const f16* aSrc = h_ex + (b0 + lo) * H_ + (hi << 3);

  for (int ts = 0; ts < T_; ++ts) {
    // xp prefetch (flag-independent, rides into the vmcnt(0) below)
    const f16* xq = xpb + (((ts << 6) + b0 + (hi << 2)) << 9) + myrow;
    f16 x0 = xq[0], x1 = xq[H_], x2 = xq[2 * H_], x3 = xq[3 * H_];
    // wait for all 16 producers of h_ex[ts] in this batch-group
    {
      const uint32_t tgt = 16u * (uint32_t)(ts + 1);
      while (__hip_atomic_load(flg, __ATOMIC_RELAXED,
                               __HIP_MEMORY_SCOPE_AGENT) < tgt)
        __builtin_amdgcn_s_sleep(1);
      (void)__hip_atomic_load(flg, __ATOMIC_ACQUIRE, __HIP_MEMORY_SCOPE_AGENT);
    }
    // stage A: 16 x global_load_lds dwordx4 (per-lane src, linear dest)
    const f16* ap = aSrc + (size_t)ts * (B_ * H_);
#pragma unroll
    for (int kk = 0; kk < 16; kk++)
      __builtin_amdgcn_global_load_lds(
          (const __attribute__((address_space(1))) uint32_t*)(ap + (kk << 5)),
          (__attribute__((address_space(3))) uint32_t*)&lds_a[w][kk][0],
          16, 0, 0);
    asm volatile("s_waitcnt vmcnt(0)" ::: "memory");
    __builtin_amdgcn_sched_barrier(0);
    // 16 MFMAs, 2 acc chains
    f32x4 ac0 = {0.f, 0.f, 0.f, 0.f}, ac1 = {0.f, 0.f, 0.f, 0.f};
#pragma unroll
    for (int kk = 0; kk < 16; kk += 2) {
      f16x8 a0 = *(const f16x8*)&lds_a[w][kk][l << 3];
      f16x8 a1 = *(const f16x8*)&lds_a[w][kk + 1][l << 3];
      ac0 = __builtin_amdgcn_mfma_f32_16x16x32_f16(a0, Bf[kk], ac0, 0, 0, 0);
      ac1 = __builtin_amdgcn_mfma_f32_16x16x32_f16(a1, Bf[kk + 1], ac1, 0, 0, 0);
    }
    // D layout: m(batch sub) = hi*4 + reg, n(row) = lo  -> reg == acc index
    float pre0 = ac0[0] + ac1[0] + (float)x0;
    float pre1 = ac0[1] + ac1[1] + (float)x1;
    float pre2 = ac0[2] + ac1[2] + (float)x2;
    float pre3 = ac0[3] + ac1[3] + (float)x3;
    hv0 = (1.0f - ALPHA_) * hv0 + ALPHA_ * tanhfast(pre0);
    hv1 = (1.0f - ALPHA_) * hv1 + ALPHA_ * tanhfast(pre1);
    hv2 = (1.0f - ALPHA_) * hv2 + ALPHA_ * tanhfast(pre2);
    hv3 = (1.0f - ALPHA_) * hv3 + ALPHA_ * tanhfast(pre3);
    f16* hw = h_ex + (size_t)(ts + 1) * (B_ * H_) + (b0 + (hi << 2)) * H_ + myrow;
    hw[0] = (f16)hv0; hw[H_] = (f16)hv1;
    hw[2 * H_] = (f16)hv2; hw[3 * H_] = (f16)hv3;
    __syncthreads();  // drains vmcnt: all h stores of both waves in L2
    if (t == 0 && ts + 1 < T_)
      __hip_atomic_fetch_add(flg, 1u, __ATOMIC_RELEASE,
                             __HIP_MEMORY_SCOPE_AGENT);
  }
  float* hf = hfin + (b0 + (hi << 2)) * H_ + myrow;
  hf[0] = hv0; hf[H_] = hv1; hf[2 * H_] = hv2; hf[3 * H_] = hv3;
}

// ---------------------------------------------------------------------------
// out[b, ts, o] = sum_h hall[ts][b][h] * W_out[o, h] + b_out[o]
// ---------------------------------------------------------------------------
__global__ __launch_bounds__(256) void outgemm_k(
    const f16* __restrict__ hall, const uint32_t* __restrict__ woutT,
    const float* __restrict__ bout, float* __restrict__ out) {
  __shared__ uint32_t A[32][256];
  const int bid = blockIdx.x;
  const int b = bid >> 4, ts0 = (bid & 15) * 32;
  const int t = threadIdx.x, o = t & 63, g = t >> 6;
  const uint32_t* hp = (const uint32_t*)hall;
#pragma unroll
  for (int i = 0; i < 32; i++) {
    int id = i * 256 + t;
    int r = id >> 8, k = id & 255;
    A[r][k] = hp[(ts0 + r) * (B_ * H_ / 2) + b * (H_ / 2) + k];
  }
  const float bo = bout[o];
  __syncthreads();
  float acc[8];
#pragma unroll
  for (int r = 0; r < 8; r++) acc[r] = 0.f;
  for (int k4 = 0; k4 < 64; k4++) {
    uint32_t w0 = woutT[(4 * k4 + 0) * 64 + o];
    uint32_t w1 = woutT[(4 * k4 + 1) * 64 + o];
    uint32_t w2 = woutT[(4 * k4 + 2) * 64 + o];
    uint32_t w3 = woutT[(4 * k4 + 3) * 64 + o];
#pragma unroll
    for (int r = 0; r < 8; r++) {
      uint4 hq = *((const uint4*)&A[g * 8 + r][k4 * 4]);
      acc[r] = dot2(w0, hq.x, acc[r]);
      acc[r] = dot2(w1, hq.y, acc[r]);
      acc[r] = dot2(w2, hq.z, acc[r]);
      acc[r] = dot2(w3, hq.w, acc[r]);
    }
  }
#pragma unroll
  for (int r = 0; r < 8; r++)
    out[(b * T_ + ts0 + g * 8 + r) * O_ + o] = acc[r] + bo;
}

extern "C" void kernel_launch(void* const* d_in, const int* in_sizes, int n_in,
                              void* d_out, int out_size, void* d_ws,
                              size_t ws_size, hipStream_t stream) {
  const float* inputs = (const float*)d_in[0];  // [B,T,I]
  const float* h0     = (const float*)d_in[1];  // [B,H]
  const float* Win    = (const float*)d_in[2];  // [H,I]
  const float* Wrec   = (const float*)d_in[3];  // [H,H]
  const float* bias   = (const float*)d_in[4];  // [H]
  const float* Wout   = (const float*)d_in[5];  // [O,H]
  const float* bout   = (const float*)d_in[6];  // [O]
  float* out = (float*)d_out;                   // [B,T,O] then [B,H]

  uint8_t* ws = (uint8_t*)d_ws;
  uint32_t* wrecM = (uint32_t*)(ws);                   // 512 KB
  uint32_t* winT  = (uint32_t*)(ws + (512u << 10));    // 128 KB
  uint32_t* woutT = (uint32_t*)(ws + (640u << 10));    //  64 KB
  uint32_t* flags = (uint32_t*)(ws + (704u << 10));    // 512 B (4 groups)
  f16* xpb  = (f16*)(ws + (1u << 20));                 // 32 MB [T][B][H]
  f16* h_ex = (f16*)(ws + (33u << 20));                // 33.6 MB [T+1][B][H]

  hipMemsetAsync(flags, 0, 512, stream);
  hipLaunchKernelGGL(pack_w, dim3(704), dim3(256), 0, stream, Wrec, Win, Wout,
                     wrecM, winT, woutT);
  hipLaunchKernelGGL(xproj_k, dim3((B_ * T_) / 32), dim3(512), 0, stream,
                     inputs, winT, bias, xpb);
  hipLaunchKernelGGL(rnn_k, dim3(64), dim3(128), 0, stream,
                     (const f16x8*)wrecM, xpb, h0, h_ex, flags,
                     out + B_ * T_ * O_);
  hipLaunchKernelGGL(outgemm_k, dim3(B_ * (T_ / 32)), dim3(256), 0, stream,
                     h_ex + B_ * H_, woutT, bout, out);
}

// Round 10
// 1502.160 us; speedup vs baseline: 2.1219x; 1.7559x over previous
//
#include <hip/hip_runtime.h>
#include <stdint.h>

#define B_ 64
#define T_ 512
#define I_ 128
#define H_ 512
#define O_ 64
#define ALPHA_ 0.1f

typedef _Float16 f16;
typedef _Float16 f16x8 __attribute__((ext_vector_type(8)));
typedef float f32x4 __attribute__((ext_vector_type(4)));

// wrecM: MFMA B-fragments, u32 pairs. id -> p=id&3, l=(id>>2)&63,
//   kk=(id>>8)&15, r2w=id>>12 (0..31):
//   row = (r2w>>1)*32 + (r2w&1)*16 + (l&15)   [output row n]
//   col = kk*32 + (l>>4)*8 + 2p               [k index]
#define WRECM_U32 131072
#define WIN_END   (WRECM_U32 + 32768)
#define WOUT_END  (WIN_END + 16384)

__device__ __forceinline__ uint32_t pkf16(float a, float b) {
  f16 ha = (f16)a, hb = (f16)b;
  uint16_t ua = __builtin_bit_cast(uint16_t, ha);
  uint16_t ub = __builtin_bit_cast(uint16_t, hb);
  return (uint32_t)ua | ((uint32_t)ub << 16);
}

__device__ __forceinline__ float dot2(uint32_t w, uint32_t h, float acc) {
#if __has_builtin(__builtin_amdgcn_fdot2)
  typedef _Float16 f16x2 __attribute__((ext_vector_type(2)));
  return __builtin_amdgcn_fdot2(__builtin_bit_cast(f16x2, w),
                                __builtin_bit_cast(f16x2, h), acc, false);
#else
  return acc;
#endif
}

__device__ __forceinline__ float tanhfast(float x) {
  float e = __expf(2.0f * x);
#if __has_builtin(__builtin_amdgcn_rcpf)
  return 1.0f - 2.0f * __builtin_amdgcn_rcpf(e + 1.0f);
#else
  return 1.0f - 2.0f / (e + 1.0f);
#endif
}

// Device-coherent f16 store: writes through to the coherence point (sc0 sc1)
// so consumers on other XCDs see it without any L2 writeback/invalidate ops.
__device__ __forceinline__ void sc_store_f16(f16* p, f16 v) {
  uint32_t u = (uint32_t)__builtin_bit_cast(uint16_t, v);
  asm volatile("global_store_short %0, %1, off sc0 sc1"
               :: "v"(p), "v"(u) : "memory");
}

// ---------------------------------------------------------------------------
__global__ __launch_bounds__(256) void pack_w(
    const float* __restrict__ Wrec, const float* __restrict__ Win,
    const float* __restrict__ Wout, uint32_t* __restrict__ wrecM,
    uint32_t* __restrict__ winT, uint32_t* __restrict__ woutT) {
  int id = blockIdx.x * 256 + threadIdx.x;
  if (id < WRECM_U32) {
    int p = id & 3, l = (id >> 2) & 63, kk = (id >> 8) & 15, r2w = id >> 12;
    int row = (r2w >> 1) * 32 + (r2w & 1) * 16 + (l & 15);
    int col = kk * 32 + (l >> 4) * 8 + 2 * p;
    const float* s = Wrec + row * 512 + col;
    wrecM[id] = pkf16(s[0], s[1]);
  } else if (id < WIN_END) {
    int e = id - WRECM_U32;
    int n = e >> 6, k = e & 63;
    const float* s = Win + n * 128 + 2 * k;
    winT[k * 512 + n] = pkf16(s[0], s[1]);
  } else if (id < WOUT_END) {
    int e = id - WIN_END;
    int o = e >> 8, k = e & 255;
    const float* s = Wout + o * 512 + 2 * k;
    woutT[k * 64 + o] = pkf16(s[0], s[1]);
  }
}

// ---------------------------------------------------------------------------
// x_proj with bias folded: xpb[ts][b][n] = sum_i in[b,ts,i]*W_in[n,i] + b[n]
// ---------------------------------------------------------------------------
__global__ __launch_bounds__(512) void xproj_k(
    const float* __restrict__ in, const uint32_t* __restrict__ winT,
    const float* __restrict__ bias, f16* __restrict__ xpb) {
  __shared__ uint32_t A[32][64];
  const int t = threadIdx.x;
  const int m0 = blockIdx.x * 32;
#pragma unroll
  for (int i = 0; i < 4; i++) {
    int id = i * 512 + t;
    int r = id >> 6, k = id & 63;
    const float* s = in + (m0 + r) * I_ + 2 * k;
    A[r][k] = pkf16(s[0], s[1]);
  }
  uint32_t w[64];
#pragma unroll
  for (int k = 0; k < 64; k++) w[k] = winT[k * 512 + t];
  const float bia = bias[t];
  __syncthreads();
  for (int r = 0; r < 32; r++) {
    float a0 = 0.f, a1 = 0.f, a2 = 0.f, a3 = 0.f;
#pragma unroll
    for (int k4 = 0; k4 < 16; k4++) {
      uint4 hq = *((const uint4*)&A[r][k4 * 4]);
      a0 = dot2(w[4 * k4 + 0], hq.x, a0);
      a1 = dot2(w[4 * k4 + 1], hq.y, a1);
      a2 = dot2(w[4 * k4 + 2], hq.z, a2);
      a3 = dot2(w[4 * k4 + 3], hq.w, a3);
    }
    int m = m0 + r, b = m >> 9, ts = m & 511;
    xpb[(((ts << 6) + b) << 9) + t] = (f16)(((a0 + a1) + (a2 + a3)) + bia);
  }
}

// ---------------------------------------------------------------------------
// Recurrence via MFMA: 64 WGs = 4 batch-groups (c) x 16 h-slices (r), 128 thr
// = 2 waves. Wave w computes pre[batch 16][rows r*32+w*16 .. +16] as
// D = A(h[16,512]) x B(W^T) with 16 chained mfma_f32_16x16x32_f16.
// B fragments (64 VGPR/lane) loaded ONCE. A staged per step via
// global_load_lds (per-lane src = A-fragment addr, linear LDS dest).
// Step sync: RELAXED flag add/poll only — NO acquire/release (those compile
// to per-step L2 invalidate/writeback, the r9 5.1us/step cost). Coherence:
// h stores are sc0/sc1 write-through; consumer lines are fresh addresses
// (h_ex[ts] never previously cached by any consumer within a launch), so
// plain loads miss to the coherence point and see the data. syncthreads'
// vmcnt(0) drain orders all sc-stores before lane 0's flag add.
// ---------------------------------------------------------------------------
__global__ __launch_bounds__(128) void rnn_k(
    const f16x8* __restrict__ wrecM, const f16* __restrict__ xpb,
    const float* __restrict__ h0, f16* __restrict__ h_ex,
    uint32_t* __restrict__ flags, float* __restrict__ hfin) {
  __shared__ f16 lds_a[2][16][512];  // [wave][kk][A-frag 1KB] = 32 KB
  const int bid = blockIdx.x, c = bid & 3, r = bid >> 2;
  const int t = threadIdx.x, l = t & 63, w = t >> 6;
  const int lo = l & 15, hi = l >> 4;
  const int b0 = c << 4;
  const int myrow = (r << 5) + (w << 4) + lo;  // output row n of this lane

  // resident B fragments: Bf[kk][j] = W_rec[myrow][kk*32 + hi*8 + j]
  f16x8 Bf[16];
  const f16x8* wp = wrecM + ((((r << 1) + w) << 4) << 6) + l;
#pragma unroll
  for (int kk = 0; kk < 16; kk++) Bf[kk] = wp[kk << 6];

  // master h (f32): lane owns batch b0+hi*4+reg (reg=0..3), row myrow
  float hv0, hv1, hv2, hv3;
  {
    const float* hp = h0 + (b0 + (hi << 2)) * H_ + myrow;
    hv0 = hp[0]; hv1 = hp[H_]; hv2 = hp[2 * H_]; hv3 = hp[3 * H_];
    f16* he = h_ex + (b0 + (hi << 2)) * H_ + myrow;
    sc_store_f16(he + 0, (f16)hv0);
    sc_store_f16(he + H_, (f16)hv1);
    sc_store_f16(he + 2 * H_, (f16)hv2);
    sc_store_f16(he + 3 * H_, (f16)hv3);
  }
  uint32_t* flg = flags + (c << 5);  // 128-B spaced per group
  __syncthreads();                   // drains vmcnt: init publishes retired
  if (t == 0)
    __hip_atomic_fetch_add(flg, 1u, __ATOMIC_RELAXED, __HIP_MEMORY_SCOPE_AGENT);

  // A source: lane reads h_ex[ts][b0+lo][kk*32 + hi*8 .. +8]
  const f16* aSrc = h_ex + (b0 + lo) * H_ + (hi << 3);

  for (int ts = 0; ts < T_; ++ts) {
    // xp prefetch (flag-independent, rides into the vmcnt(0) below)
    const f16* xq = xpb + (((ts << 6) + b0 + (hi << 2)) << 9) + myrow;
    f16 x0 = xq[0], x1 = xq[H_], x2 = xq[2 * H_], x3 = xq[3 * H_];
    // wait for all 16 producers of h_ex[ts] in this batch-group
    {
      const uint32_t tgt = 16u * (uint32_t)(ts + 1);
      while (__hip_atomic_load(flg, __ATOMIC_RELAXED,
                               __HIP_MEMORY_SCOPE_AGENT) < tgt)
        __builtin_amdgcn_s_sleep(1);
    }
    asm volatile("" ::: "memory");  // no hoisting of loads above the spin
    // stage A: 16 x global_load_lds dwordx4 (per-lane src, linear dest)
    const f16* ap = aSrc + (size_t)ts * (B_ * H_);
#pragma unroll
    for (int kk = 0; kk < 16; kk++)
      __builtin_amdgcn_global_load_lds(
          (const __attribute__((address_space(1))) uint32_t*)(ap + (kk << 5)),
          (__attribute__((address_space(3))) uint32_t*)&lds_a[w][kk][0],
          16, 0, 0);
    asm volatile("s_waitcnt vmcnt(0)" ::: "memory");
    __builtin_amdgcn_sched_barrier(0);
    // 16 MFMAs, 2 acc chains
    f32x4 ac0 = {0.f, 0.f, 0.f, 0.f}, ac1 = {0.f, 0.f, 0.f, 0.f};
#pragma unroll
    for (int kk = 0; kk < 16; kk += 2) {
      f16x8 a0 = *(const f16x8*)&lds_a[w][kk][l << 3];
      f16x8 a1 = *(const f16x8*)&lds_a[w][kk + 1][l << 3];
      ac0 = __builtin_amdgcn_mfma_f32_16x16x32_f16(a0, Bf[kk], ac0, 0, 0, 0);
      ac1 = __builtin_amdgcn_mfma_f32_16x16x32_f16(a1, Bf[kk + 1], ac1, 0, 0, 0);
    }
    // D layout: m(batch sub) = hi*4 + reg, n(row) = lo  -> reg == acc index
    float pre0 = ac0[0] + ac1[0] + (float)x0;
    float pre1 = ac0[1] + ac1[1] + (float)x1;
    float pre2 = ac0[2] + ac1[2] + (float)x2;
    float pre3 = ac0[3] + ac1[3] + (float)x3;
    hv0 = (1.0f - ALPHA_) * hv0 + ALPHA_ * tanhfast(pre0);
    hv1 = (1.0f - ALPHA_) * hv1 + ALPHA_ * tanhfast(pre1);
    hv2 = (1.0f - ALPHA_) * hv2 + ALPHA_ * tanhfast(pre2);
    hv3 = (1.0f - ALPHA_) * hv3 + ALPHA_ * tanhfast(pre3);
    f16* hw = h_ex + (size_t)(ts + 1) * (B_ * H_) + (b0 + (hi << 2)) * H_ + myrow;
    sc_store_f16(hw + 0, (f16)hv0);
    sc_store_f16(hw + H_, (f16)hv1);
    sc_store_f16(hw + 2 * H_, (f16)hv2);
    sc_store_f16(hw + 3 * H_, (f16)hv3);
    __syncthreads();  // vmcnt(0) per wave: all sc-stores retired at L3
    if (t == 0 && ts + 1 < T_)
      __hip_atomic_fetch_add(flg, 1u, __ATOMIC_RELAXED,
                             __HIP_MEMORY_SCOPE_AGENT);
  }
  float* hf = hfin + (b0 + (hi << 2)) * H_ + myrow;
  hf[0] = hv0; hf[H_] = hv1; hf[2 * H_] = hv2; hf[3 * H_] = hv3;
}

// ---------------------------------------------------------------------------
// out[b, ts, o] = sum_h hall[ts][b][h] * W_out[o, h] + b_out[o]
// ---------------------------------------------------------------------------
__global__ __launch_bounds__(256) void outgemm_k(
    const f16* __restrict__ hall, const uint32_t* __restrict__ woutT,
    const float* __restrict__ bout, float* __restrict__ out) {
  __shared__ uint32_t A[32][256];
  const int bid = blockIdx.x;
  const int b = bid >> 4, ts0 = (bid & 15) * 32;
  const int t = threadIdx.x, o = t & 63, g = t >> 6;
  const uint32_t* hp = (const uint32_t*)hall;
#pragma unroll
  for (int i = 0; i < 32; i++) {
    int id = i * 256 + t;
    int r = id >> 8, k = id & 255;
    A[r][k] = hp[(ts0 + r) * (B_ * H_ / 2) + b * (H_ / 2) + k];
  }
  const float bo = bout[o];
  __syncthreads();
  float acc[8];
#pragma unroll
  for (int r = 0; r < 8; r++) acc[r] = 0.f;
  for (int k4 = 0; k4 < 64; k4++) {
    uint32_t w0 = woutT[(4 * k4 + 0) * 64 + o];
    uint32_t w1 = woutT[(4 * k4 + 1) * 64 + o];
    uint32_t w2 = woutT[(4 * k4 + 2) * 64 + o];
    uint32_t w3 = woutT[(4 * k4 + 3) * 64 + o];
#pragma unroll
    for (int r = 0; r < 8; r++) {
      uint4 hq = *((const uint4*)&A[g * 8 + r][k4 * 4]);
      acc[r] = dot2(w0, hq.x, acc[r]);
      acc[r] = dot2(w1, hq.y, acc[r]);
      acc[r] = dot2(w2, hq.z, acc[r]);
      acc[r] = dot2(w3, hq.w, acc[r]);
    }
  }
#pragma unroll
  for (int r = 0; r < 8; r++)
    out[(b * T_ + ts0 + g * 8 + r) * O_ + o] = acc[r] + bo;
}

extern "C" void kernel_launch(void* const* d_in, const int* in_sizes, int n_in,
                              void* d_out, int out_size, void* d_ws,
                              size_t ws_size, hipStream_t stream) {
  const float* inputs = (const float*)d_in[0];  // [B,T,I]
  const float* h0     = (const float*)d_in[1];  // [B,H]
  const float* Win    = (const float*)d_in[2];  // [H,I]
  const float* Wrec   = (const float*)d_in[3];  // [H,H]
  const float* bias   = (const float*)d_in[4];  // [H]
  const float* Wout   = (const float*)d_in[5];  // [O,H]
  const float* bout   = (const float*)d_in[6];  // [O]
  float* out = (float*)d_out;                   // [B,T,O] then [B,H]

  uint8_t* ws = (uint8_t*)d_ws;
  uint32_t* wrecM = (uint32_t*)(ws);                   // 512 KB
  uint32_t* winT  = (uint32_t*)(ws + (512u << 10));    // 128 KB
  uint32_t* woutT = (uint32_t*)(ws + (640u << 10));    //  64 KB
  uint32_t* flags = (uint32_t*)(ws + (704u << 10));    // 512 B (4 groups)
  f16* xpb  = (f16*)(ws + (1u << 20));                 // 32 MB [T][B][H]
  f16* h_ex = (f16*)(ws + (33u << 20));                // 33.6 MB [T+1][B][H]

  hipMemsetAsync(flags, 0, 512, stream);
  hipLaunchKernelGGL(pack_w, dim3(704), dim3(256), 0, stream, Wrec, Win, Wout,
                     wrecM, winT, woutT);
  hipLaunchKernelGGL(xproj_k, dim3((B_ * T_) / 32), dim3(512), 0, stream,
                     inputs, winT, bias, xpb);
  hipLaunchKernelGGL(rnn_k, dim3(64), dim3(128), 0, stream,
                     (const f16x8*)wrecM, xpb, h0, h_ex, flags,
                     out + B_ * T_ * O_);
  hipLaunchKernelGGL(outgemm_k, dim3(B_ * (T_ / 32)), dim3(256), 0, stream,
                     h_ex + B_ * H_, woutT, bout, out);
}

// Round 12
// 1025.773 us; speedup vs baseline: 3.1074x; 1.4644x over previous
//
#include <hip/hip_runtime.h>
#include <stdint.h>

#define B_ 64
#define T_ 512
#define I_ 128
#define H_ 512
#define O_ 64
#define ALPHA_ 0.1f

// K-split recurrence: 8 waves; wave wv owns h-pair slice [32wv, 32wv+32)
// (8 quads q0..q7). Lane l computes rows {64j+l}, j=0..7.
// Weights per lane: 256 pairs = 192 resident VGPRs (quads q0..q5, 24/row)
// + 64 pairs in LDS (quads q6,q7 -> 16 ds_read_b128/step). NO streaming.
#define NV 24                       // resident pairs per row
#define R_DW (192 * 512)            // wrecR u32 count
#define L_END (R_DW + 64 * 512)     // + wrecL u32 count (16 quads/lane)
#define WIN_END (L_END + 512 * 64)
#define WOUT_END (WIN_END + 64 * 256)

typedef _Float16 f16;
typedef _Float16 f16x2 __attribute__((ext_vector_type(2)));

__device__ __forceinline__ uint32_t pkf16(float a, float b) {
  f16 ha = (f16)a, hb = (f16)b;
  uint16_t ua = __builtin_bit_cast(uint16_t, ha);
  uint16_t ub = __builtin_bit_cast(uint16_t, hb);
  return (uint32_t)ua | ((uint32_t)ub << 16);
}

__device__ __forceinline__ float dot2(uint32_t w, uint32_t h, float acc) {
#if __has_builtin(__builtin_amdgcn_fdot2)
  return __builtin_amdgcn_fdot2(__builtin_bit_cast(f16x2, w),
                                __builtin_bit_cast(f16x2, h), acc, false);
#else
  f16x2 wv = __builtin_bit_cast(f16x2, w), hv = __builtin_bit_cast(f16x2, h);
  return acc + (float)wv[0] * (float)hv[0] + (float)wv[1] * (float)hv[1];
#endif
}

__device__ __forceinline__ float tanhfast(float x) {
  float e = __expf(2.0f * x);   // inf-safe at both ends
#if __has_builtin(__builtin_amdgcn_rcpf)
  return 1.0f - 2.0f * __builtin_amdgcn_rcpf(e + 1.0f);
#else
  return 1.0f - 2.0f / (e + 1.0f);
#endif
}

#define DOT4S(A, S, HQ)                                             \
  A = dot2((S).w, (HQ).w,                                           \
      dot2((S).z, (HQ).z, dot2((S).y, (HQ).y, dot2((S).x, (HQ).x, A))))

// ---------------------------------------------------------------------------
// Pack weights (f16x2 pairs):
//  wrecR[(j*24+c)*512 + t] = W_rec[64j+(t&63)][2*(32*(t>>6)+c) ..+1], c<24
//  wrecL u32 e: comp=e&3, i4=e>>2, t=i4&511, qj=i4>>9 (0..15), j=qj>>1,
//    qq=qj&1 -> pair = 32*(t>>6) + 24 + 4*qq + comp
//  winT [k*512 + n] = W_in[n][2k..+1]
//  woutT[k*64  + o] = W_out[o][2k..+1]
// ---------------------------------------------------------------------------
__global__ __launch_bounds__(256) void pack_w(
    const float* __restrict__ Wrec, const float* __restrict__ Win,
    const float* __restrict__ Wout, uint32_t* __restrict__ wrecR,
    uint32_t* __restrict__ wrecL, uint32_t* __restrict__ winT,
    uint32_t* __restrict__ woutT) {
  int id = blockIdx.x * 256 + threadIdx.x;
  if (id < R_DW) {
    int t = id & 511, cj = id >> 9;
    int j = cj / NV, c = cj % NV;
    int row = 64 * j + (t & 63), col = 64 * (t >> 6) + 2 * c;
    const float* s = Wrec + row * 512 + col;
    wrecR[id] = pkf16(s[0], s[1]);
  } else if (id < L_END) {
    int e = id - R_DW;
    int comp = e & 3, i4 = e >> 2;
    int t = i4 & 511, qj = i4 >> 9;     // qj in [0,16)
    int j = qj >> 1, qq = qj & 1;
    int row = 64 * j + (t & 63);
    int col = 64 * (t >> 6) + 2 * (NV + 4 * qq + comp);
    const float* s = Wrec + row * 512 + col;
    wrecL[e] = pkf16(s[0], s[1]);
  } else if (id < WIN_END) {
    int e = id - L_END;
    int n = e >> 6, k = e & 63;
    const float* s = Win + n * 128 + 2 * k;
    winT[k * 512 + n] = pkf16(s[0], s[1]);
  } else {
    int e = id - WIN_END;
    int o = e >> 8, k = e & 255;
    const float* s = Wout + o * 512 + 2 * k;
    woutT[k * 64 + o] = pkf16(s[0], s[1]);
  }
}

// ---------------------------------------------------------------------------
// x_proj: xp[m, n] = sum_i inputs[m, i] * W_in[n, i]   (m = b*T+ts, f16 out)
// ---------------------------------------------------------------------------
__global__ __launch_bounds__(512) void xproj_k(
    const float* __restrict__ in, const uint32_t* __restrict__ winT,
    f16* __restrict__ xp) {
  __shared__ uint32_t A[32][64];
  const int t = threadIdx.x;
  const int m0 = blockIdx.x * 32;
#pragma unroll
  for (int i = 0; i < 4; i++) {
    int id = i * 512 + t;
    int r = id >> 6, k = id & 63;
    const float* s = in + (m0 + r) * I_ + 2 * k;
    A[r][k] = pkf16(s[0], s[1]);
  }
  uint32_t w[64];
#pragma unroll
  for (int k = 0; k < 64; k++) w[k] = winT[k * 512 + t];
  __syncthreads();
  for (int r = 0; r < 32; r++) {
    float a0 = 0.f, a1 = 0.f, a2 = 0.f, a3 = 0.f;
#pragma unroll
    for (int k4 = 0; k4 < 16; k4++) {
      uint4 hq = *((const uint4*)&A[r][k4 * 4]);
      a0 = dot2(w[4 * k4 + 0], hq.x, a0);
      a1 = dot2(w[4 * k4 + 1], hq.y, a1);
      a2 = dot2(w[4 * k4 + 2], hq.z, a2);
      a3 = dot2(w[4 * k4 + 3], hq.w, a3);
    }
    xp[(m0 + r) * H_ + t] = (f16)((a0 + a1) + (a2 + a3));
  }
}

// ---------------------------------------------------------------------------
// Recurrence, K-split, NO streaming (spill-proof: ~230 live regs):
//  - wave wv reads 6 uniform h-quads for resident weights + 2 for LDS weights
//  - 16 per-lane ds_read_b128 weight quads (the only bulk LDS traffic)
//  - partials pld[8][512] single-buffered; 2 lgkm-only barriers/step
//  - h single-buffered (slice written by its own wave); xp prefetch + hall
//    store ride across the barriers (vm never drained in-loop)
// ---------------------------------------------------------------------------
__global__ __attribute__((amdgpu_flat_work_group_size(512, 512),
                          amdgpu_waves_per_eu(2, 2)))
void rnn_k(const uint32_t* __restrict__ wrecR, const uint4* __restrict__ wrecL4,
           const f16* __restrict__ xp, const float* __restrict__ bias,
           const float* __restrict__ h0, f16* __restrict__ hall,
           float* __restrict__ hfin) {
  extern __shared__ uint32_t lds[];
  uint32_t* hbuf = lds;                       // 256 u32 = h[512] f16 (1 KB)
  float* pld = (float*)(lds + 256);           // [8][512] f32 (16 KB)
  uint4* wq = (uint4*)(lds + 256 + 4096);     // [16][512] uint4 (128 KB)
  const int b = blockIdx.x, t = threadIdx.x;
  const int l = t & 63, wv = t >> 6;

  uint32_t wr[8][NV];  // 192 resident weight pairs
#pragma unroll
  for (int j = 0; j < 8; j++)
#pragma unroll
    for (int c = 0; c < NV; c++) wr[j][c] = wrecR[(j * NV + c) * 512 + t];
#pragma unroll
  for (int k = 0; k < 16; k++) wq[k * 512 + t] = wrecL4[k * 512 + t];

  float hv = h0[b * H_ + t];
  const float bia = bias[t];
  ((f16*)hbuf)[t] = (f16)hv;

  const f16* xpp = xp + b * (T_ * H_) + t;
  f16* hap = hall + b * H_ + t;
  float xv = (float)xpp[0];
  const uint32_t* hqb = hbuf + (wv << 5);  // this wave's 32 h-pairs
  __syncthreads();

  for (int ts = 0; ts < T_; ++ts) {
    float acc[8];
#pragma unroll
    for (int j = 0; j < 8; j++) acc[j] = 0.f;
    // ---- resident quads q0..q5 (uniform broadcast reads) ----
#pragma unroll
    for (int q = 0; q < 6; q++) {
      uint4 hq = *((const uint4*)(hqb + 4 * q));
#pragma unroll
      for (int j = 0; j < 8; j++)
        acc[j] = dot2(wr[j][4 * q + 3], hq.w,
                 dot2(wr[j][4 * q + 2], hq.z,
                 dot2(wr[j][4 * q + 1], hq.y,
                 dot2(wr[j][4 * q + 0], hq.x, acc[j]))));
    }
    // ---- LDS weight quads q6,q7 (per-lane b128, conflict-free) ----
    {
      uint4 hq6 = *((const uint4*)(hqb + 24));
      uint4 hq7 = *((const uint4*)(hqb + 28));
#pragma unroll
      for (int j = 0; j < 8; j++) {
        uint4 w6 = wq[(2 * j + 0) * 512 + t];
        DOT4S(acc[j], w6, hq6);
        uint4 w7 = wq[(2 * j + 1) * 512 + t];
        DOT4S(acc[j], w7, hq7);
      }
    }
    // ---- partial writes: pld[wv][64j+l] (consecutive lanes, no conflict) --
#pragma unroll
    for (int j = 0; j < 8; j++) pld[(wv << 9) + (j << 6) + l] = acc[j];
    float xn = 0.f;
    if (ts + 1 < T_) xn = (float)xpp[(ts + 1) * H_];  // vm, rides barriers
    asm volatile("s_waitcnt lgkmcnt(0)" ::: "memory");
    __builtin_amdgcn_s_barrier();
    asm volatile("" ::: "memory");
    // ---- reduce: thread t owns row t ----
    float s01 = pld[(0 << 9) + t] + pld[(1 << 9) + t];
    float s23 = pld[(2 << 9) + t] + pld[(3 << 9) + t];
    float s45 = pld[(4 << 9) + t] + pld[(5 << 9) + t];
    float s67 = pld[(6 << 9) + t] + pld[(7 << 9) + t];
    float pre = ((s01 + s23) + (s45 + s67)) + bia + xv;
    hv = (1.0f - ALPHA_) * hv + ALPHA_ * tanhfast(pre);
    f16 hh = (f16)hv;
    ((f16*)hbuf)[t] = hh;        // own-slice update (single buffer)
    hap[ts * (B_ * H_)] = hh;    // hall[ts][b][t] (vm store, rides barrier)
    xv = xn;
    asm volatile("s_waitcnt lgkmcnt(0)" ::: "memory");
    __builtin_amdgcn_s_barrier();
    asm volatile("" ::: "memory");
  }
  hfin[b * H_ + t] = hv;
}

// ---------------------------------------------------------------------------
// out[b, ts, o] = sum_h hall[ts][b][h] * W_out[o, h] + b_out[o]
// ---------------------------------------------------------------------------
__global__ __launch_bounds__(256) void outgemm_k(
    const f16* __restrict__ hall, const uint32_t* __restrict__ woutT,
    const float* __restrict__ bout, float* __restrict__ out) {
  __shared__ uint32_t A[32][256];
  const int bid = blockIdx.x;
  const int b = bid >> 4, ts0 = (bid & 15) * 32;
  const int t = threadIdx.x, o = t & 63, g = t >> 6;
  const uint32_t* hp = (const uint32_t*)hall;
#pragma unroll
  for (int i = 0; i < 32; i++) {
    int id = i * 256 + t;
    int r = id >> 8, k = id & 255;
    A[r][k] = hp[(ts0 + r) * (B_ * H_ / 2) + b * (H_ / 2) + k];
  }
  const float bo = bout[o];
  __syncthreads();
  float acc[8];
#pragma unroll
  for (int r = 0; r < 8; r++) acc[r] = 0.f;
  for (int k4 = 0; k4 < 64; k4++) {
    uint32_t w0 = woutT[(4 * k4 + 0) * 64 + o];
    uint32_t w1 = woutT[(4 * k4 + 1) * 64 + o];
    uint32_t w2 = woutT[(4 * k4 + 2) * 64 + o];
    uint32_t w3 = woutT[(4 * k4 + 3) * 64 + o];
#pragma unroll
    for (int r = 0; r < 8; r++) {
      uint4 hq = *((const uint4*)&A[g * 8 + r][k4 * 4]);
      acc[r] = dot2(w0, hq.x, acc[r]);
      acc[r] = dot2(w1, hq.y, acc[r]);
      acc[r] = dot2(w2, hq.z, acc[r]);
      acc[r] = dot2(w3, hq.w, acc[r]);
    }
  }
#pragma unroll
  for (int r = 0; r < 8; r++)
    out[(b * T_ + ts0 + g * 8 + r) * O_ + o] = acc[r] + bo;
}

extern "C" void kernel_launch(void* const* d_in, const int* in_sizes, int n_in,
                              void* d_out, int out_size, void* d_ws,
                              size_t ws_size, hipStream_t stream) {
  const float* inputs = (const float*)d_in[0];  // [B,T,I]
  const float* h0     = (const float*)d_in[1];  // [B,H]
  const float* Win    = (const float*)d_in[2];  // [H,I]
  const float* Wrec   = (const float*)d_in[3];  // [H,H]
  const float* bias   = (const float*)d_in[4];  // [H]
  const float* Wout   = (const float*)d_in[5];  // [O,H]
  const float* bout   = (const float*)d_in[6];  // [O]
  float* out = (float*)d_out;                   // [B,T,O] then [B,H]

  uint8_t* ws = (uint8_t*)d_ws;
  uint32_t* wrecR = (uint32_t*)(ws);                      // 384 KB
  uint32_t* wrecL = (uint32_t*)(ws + (384u << 10));       // 128 KB
  uint32_t* winT  = (uint32_t*)(ws + (512u << 10));       // 128 KB
  uint32_t* woutT = (uint32_t*)(ws + (640u << 10));       //  64 KB
  f16* xp   = (f16*)(ws + (1u << 20));                    //  32 MB [B,T,H]
  f16* hall = (f16*)(ws + (1u << 20) + (32u << 20));      //  32 MB [T,B,H]

  hipLaunchKernelGGL(pack_w, dim3(704), dim3(256), 0, stream, Wrec, Win, Wout,
                     wrecR, wrecL, winT, woutT);
  hipLaunchKernelGGL(xproj_k, dim3(32768 / 32), dim3(512), 0, stream, inputs,
                     winT, xp);
  // LDS: 1 KB hbuf + 16 KB pld + 128 KB weights = 148480 B (1 WG/CU)
  const int rnn_lds = 1024 + 16384 + 131072;
  hipFuncSetAttribute((const void*)rnn_k,
                      hipFuncAttributeMaxDynamicSharedMemorySize, rnn_lds);
  hipLaunchKernelGGL(rnn_k, dim3(B_), dim3(512), rnn_lds, stream, wrecR,
                     (const uint4*)wrecL, xp, bias, h0, hall,
                     out + B_ * T_ * O_);
  hipLaunchKernelGGL(outgemm_k, dim3(B_ * (T_ / 32)), dim3(256), 0, stream,
                     hall, woutT, bout, out);
}